// Round 1
// baseline (3442.630 us; speedup 1.0000x reference)
//
#include <hip/hip_runtime.h>
#include <math.h>

#define N_NODES 100000
#define N_EDGES 1600000
#define IN_F    512
#define HID     128

// ---------------- degrees ----------------
__global__ void degree_kernel(const int* __restrict__ src, const int* __restrict__ dst,
                              float* __restrict__ deg_src, float* __restrict__ deg_dst) {
    int e = blockIdx.x * blockDim.x + threadIdx.x;
    if (e < N_EDGES) {
        atomicAdd(&deg_src[src[e]], 1.0f);
        atomicAdd(&deg_dst[dst[e]], 1.0f);
    }
}

__global__ void norm_kernel(float* __restrict__ ds, float* __restrict__ dd) {
    int n = blockIdx.x * blockDim.x + threadIdx.x;
    if (n < N_NODES) {
        ds[n] = rsqrtf(fmaxf(ds[n], 1.0f));
        dd[n] = rsqrtf(fmaxf(dd[n], 1.0f));
    }
}

// ---------------- GEMM1: xw[n][j] = norm_src[n] * sum_k X[n][k]*W1[k][j] ----------------
// BM=64 rows, BN=128 (full width), BK=32. 256 threads, each computes 8 rows x 4 cols.
__global__ __launch_bounds__(256) void gemm1_kernel(const float* __restrict__ X,
                                                    const float* __restrict__ W1,
                                                    const float* __restrict__ norm_src,
                                                    float* __restrict__ xw) {
    __shared__ float As[64 * 32];    // [row][k]
    __shared__ float Bs[32 * 128];   // [k][col]

    const int t  = threadIdx.x;
    const int m0 = blockIdx.x * 64;
    const int rbase = (t >> 5) * 8;   // 0..56
    const int cbase = (t & 31) * 4;   // 0..124

    float4 acc[8];
#pragma unroll
    for (int i = 0; i < 8; i++) acc[i] = make_float4(0.f, 0.f, 0.f, 0.f);

    for (int kt = 0; kt < IN_F; kt += 32) {
        // load A tile: 64x32 floats = 512 float4, 2 per thread
#pragma unroll
        for (int i = 0; i < 2; i++) {
            int idx = i * 256 + t;
            int row = idx >> 3;          // 0..63
            int c4  = (idx & 7) * 4;     // 0,4,..,28
            float4 v = make_float4(0.f, 0.f, 0.f, 0.f);
            int grow = m0 + row;
            if (grow < N_NODES)
                v = *reinterpret_cast<const float4*>(&X[(size_t)grow * IN_F + kt + c4]);
            *reinterpret_cast<float4*>(&As[row * 32 + c4]) = v;
        }
        // load B tile: 32x128 floats = 1024 float4, 4 per thread
#pragma unroll
        for (int i = 0; i < 4; i++) {
            int idx = i * 256 + t;
            int row = idx >> 5;          // 0..31
            int c4  = (idx & 31) * 4;    // 0..124
            *reinterpret_cast<float4*>(&Bs[row * 128 + c4]) =
                *reinterpret_cast<const float4*>(&W1[(size_t)(kt + row) * HID + c4]);
        }
        __syncthreads();

#pragma unroll
        for (int kk = 0; kk < 32; kk++) {
            float4 b = *reinterpret_cast<const float4*>(&Bs[kk * 128 + cbase]);
#pragma unroll
            for (int i = 0; i < 8; i++) {
                float a = As[(rbase + i) * 32 + kk];
                acc[i].x += a * b.x;
                acc[i].y += a * b.y;
                acc[i].z += a * b.z;
                acc[i].w += a * b.w;
            }
        }
        __syncthreads();
    }

#pragma unroll
    for (int i = 0; i < 8; i++) {
        int row = m0 + rbase + i;
        if (row < N_NODES) {
            float s = norm_src[row];
            float4 v = acc[i];
            v.x *= s; v.y *= s; v.z *= s; v.w *= s;
            *reinterpret_cast<float4*>(&xw[(size_t)row * HID + cbase]) = v;
        }
    }
}

// ---------------- scatter1: agg1[dst[e]] += xw[src[e]], 128 feats ----------------
// one thread per (edge, 4-feature group): E*32 threads
__global__ void scatter1_kernel(const int* __restrict__ src, const int* __restrict__ dst,
                                const float* __restrict__ xw, float* __restrict__ agg1) {
    unsigned gid = blockIdx.x * blockDim.x + threadIdx.x;
    unsigned e = gid >> 5;
    if (e < N_EDGES) {
        int j4 = (gid & 31) * 4;
        int s = src[e], d = dst[e];
        float4 v = *reinterpret_cast<const float4*>(&xw[(size_t)s * HID + j4]);
        float* a = &agg1[(size_t)d * HID + j4];
        atomicAdd(a + 0, v.x);
        atomicAdd(a + 1, v.y);
        atomicAdd(a + 2, v.z);
        atomicAdd(a + 3, v.w);
    }
}

// ---------------- layer2: h=relu(agg1*nd+b1); hw2 = ns * (h @ W2)  (one wave/node) ----------------
__global__ void layer2_kernel(const float* __restrict__ agg1, const float* __restrict__ norm_dst,
                              const float* __restrict__ norm_src, const float* __restrict__ b1,
                              const float* __restrict__ W2, float* __restrict__ hw2) {
    int wave = (blockIdx.x * blockDim.x + threadIdx.x) >> 6;
    int lane = threadIdx.x & 63;
    if (wave >= N_NODES) return;
    float nd = norm_dst[wave];
    float acc0 = 0.f, acc1 = 0.f;
#pragma unroll
    for (int jj = 0; jj < 2; jj++) {
        int j = lane + jj * 64;
        float h = fmaxf(agg1[(size_t)wave * HID + j] * nd + b1[j], 0.f);
        acc0 += h * W2[j * 2 + 0];
        acc1 += h * W2[j * 2 + 1];
    }
#pragma unroll
    for (int off = 32; off > 0; off >>= 1) {
        acc0 += __shfl_down(acc0, off);
        acc1 += __shfl_down(acc1, off);
    }
    if (lane == 0) {
        float ns = norm_src[wave];
        hw2[wave * 2 + 0] = acc0 * ns;
        hw2[wave * 2 + 1] = acc1 * ns;
    }
}

// ---------------- scatter2: agg2[dst[e]] += hw2[src[e]], 2 feats ----------------
__global__ void scatter2_kernel(const int* __restrict__ src, const int* __restrict__ dst,
                                const float* __restrict__ hw2, float* __restrict__ agg2) {
    int e = blockIdx.x * blockDim.x + threadIdx.x;
    if (e < N_EDGES) {
        int s = src[e], d = dst[e];
        float2 v = *reinterpret_cast<const float2*>(&hw2[(size_t)s * 2]);
        atomicAdd(&agg2[(size_t)d * 2 + 0], v.x);
        atomicAdd(&agg2[(size_t)d * 2 + 1], v.y);
    }
}

// ---------------- final: softmax(agg2*nd + b2) ----------------
__global__ void softmax_kernel(const float* __restrict__ agg2, const float* __restrict__ norm_dst,
                               const float* __restrict__ b2, float* __restrict__ out) {
    int n = blockIdx.x * blockDim.x + threadIdx.x;
    if (n < N_NODES) {
        float nd = norm_dst[n];
        float z0 = agg2[n * 2 + 0] * nd + b2[0];
        float z1 = agg2[n * 2 + 1] * nd + b2[1];
        float m = fmaxf(z0, z1);
        float e0 = expf(z0 - m), e1 = expf(z1 - m);
        float inv = 1.f / (e0 + e1);
        reinterpret_cast<float2*>(out)[n] = make_float2(e0 * inv, e1 * inv);
    }
}

extern "C" void kernel_launch(void* const* d_in, const int* in_sizes, int n_in,
                              void* d_out, int out_size, void* d_ws, size_t ws_size,
                              hipStream_t stream) {
    const float* X   = (const float*)d_in[0];
    const float* W1  = (const float*)d_in[1];
    const float* b1  = (const float*)d_in[2];
    const float* W2  = (const float*)d_in[3];
    const float* b2  = (const float*)d_in[4];
    const int*   src = (const int*)d_in[5];
    const int*   dst = (const int*)d_in[6];
    float* out = (float*)d_out;

    float* ws = (float*)d_ws;
    const size_t N = N_NODES;
    float* norm_src = ws;                 // N   (starts as deg_src)
    float* norm_dst = ws + N;             // N   (starts as deg_dst)
    float* agg2     = ws + 2 * N;         // 2N
    float* xw       = ws + 4 * N;         // 128N
    float* agg1     = ws + 132 * N;       // 128N
    float* hw2      = ws + 260 * N;       // 2N

    // zero: [norm_src, norm_dst, agg2] contiguous 4N floats; agg1 128N floats
    hipMemsetAsync(ws, 0, 4 * N * sizeof(float), stream);
    hipMemsetAsync(agg1, 0, 128 * N * sizeof(float), stream);

    degree_kernel<<<(N_EDGES + 255) / 256, 256, 0, stream>>>(src, dst, norm_src, norm_dst);
    norm_kernel<<<(N_NODES + 255) / 256, 256, 0, stream>>>(norm_src, norm_dst);
    gemm1_kernel<<<(N_NODES + 63) / 64, 256, 0, stream>>>(X, W1, norm_src, xw);
    {
        unsigned total = (unsigned)N_EDGES * 32u;
        scatter1_kernel<<<(total + 255) / 256, 256, 0, stream>>>(src, dst, xw, agg1);
    }
    layer2_kernel<<<(N_NODES + 3) / 4, 256, 0, stream>>>(agg1, norm_dst, norm_src, b1, W2, hw2);
    scatter2_kernel<<<(N_EDGES + 255) / 256, 256, 0, stream>>>(src, dst, hw2, agg2);
    softmax_kernel<<<(N_NODES + 255) / 256, 256, 0, stream>>>(agg2, norm_dst, b2, out);
}

// Round 2
// 722.608 us; speedup vs baseline: 4.7642x; 4.7642x over previous
//
#include <hip/hip_runtime.h>
#include <math.h>

#define N_NODES 100000
#define N_EDGES 1600000
#define IN_F    512
#define HID     128
#define CAP     64          // bucket capacity per destination node
#define MAXOVF  (1 << 20)   // overflow edge list capacity (never used in practice)

// ---------------- build: out-degree histogram + per-dst source buckets ----------------
__global__ void build_kernel(const int* __restrict__ src, const int* __restrict__ dst,
                             int* __restrict__ outdeg, int* __restrict__ cursor,
                             int* __restrict__ bucket, int* __restrict__ ovf_cnt,
                             int* __restrict__ ovf_src, int* __restrict__ ovf_dst) {
    int e = blockIdx.x * blockDim.x + threadIdx.x;
    if (e < N_EDGES) {
        int s = src[e], d = dst[e];
        atomicAdd(&outdeg[s], 1);
        int slot = atomicAdd(&cursor[d], 1);
        if (slot < CAP) {
            bucket[(size_t)d * CAP + slot] = s;
        } else {
            int k = atomicAdd(ovf_cnt, 1);
            if (k < MAXOVF) { ovf_src[k] = s; ovf_dst[k] = d; }
        }
    }
}

// ---------------- norms from integer degrees ----------------
__global__ void norm_kernel(const int* __restrict__ outdeg, const int* __restrict__ indeg,
                            float* __restrict__ norm_src, float* __restrict__ norm_dst) {
    int n = blockIdx.x * blockDim.x + threadIdx.x;
    if (n < N_NODES) {
        norm_src[n] = rsqrtf(fmaxf((float)outdeg[n], 1.0f));
        norm_dst[n] = rsqrtf(fmaxf((float)indeg[n], 1.0f));
    }
}

// ---------------- GEMM1: xw[n][j] = norm_src[n] * sum_k X[n][k]*W1[k][j] ----------------
// BM=64 rows, BN=128 (full width), BK=32. 256 threads, each computes 8 rows x 4 cols.
__global__ __launch_bounds__(256) void gemm1_kernel(const float* __restrict__ X,
                                                    const float* __restrict__ W1,
                                                    const float* __restrict__ norm_src,
                                                    float* __restrict__ xw) {
    __shared__ float As[64 * 32];    // [row][k]
    __shared__ float Bs[32 * 128];   // [k][col]

    const int t  = threadIdx.x;
    const int m0 = blockIdx.x * 64;
    const int rbase = (t >> 5) * 8;   // 0..56
    const int cbase = (t & 31) * 4;   // 0..124

    float4 acc[8];
#pragma unroll
    for (int i = 0; i < 8; i++) acc[i] = make_float4(0.f, 0.f, 0.f, 0.f);

    for (int kt = 0; kt < IN_F; kt += 32) {
#pragma unroll
        for (int i = 0; i < 2; i++) {
            int idx = i * 256 + t;
            int row = idx >> 3;
            int c4  = (idx & 7) * 4;
            float4 v = make_float4(0.f, 0.f, 0.f, 0.f);
            int grow = m0 + row;
            if (grow < N_NODES)
                v = *reinterpret_cast<const float4*>(&X[(size_t)grow * IN_F + kt + c4]);
            *reinterpret_cast<float4*>(&As[row * 32 + c4]) = v;
        }
#pragma unroll
        for (int i = 0; i < 4; i++) {
            int idx = i * 256 + t;
            int row = idx >> 5;
            int c4  = (idx & 31) * 4;
            *reinterpret_cast<float4*>(&Bs[row * 128 + c4]) =
                *reinterpret_cast<const float4*>(&W1[(size_t)(kt + row) * HID + c4]);
        }
        __syncthreads();

#pragma unroll
        for (int kk = 0; kk < 32; kk++) {
            float4 b = *reinterpret_cast<const float4*>(&Bs[kk * 128 + cbase]);
#pragma unroll
            for (int i = 0; i < 8; i++) {
                float a = As[(rbase + i) * 32 + kk];
                acc[i].x += a * b.x;
                acc[i].y += a * b.y;
                acc[i].z += a * b.z;
                acc[i].w += a * b.w;
            }
        }
        __syncthreads();
    }

#pragma unroll
    for (int i = 0; i < 8; i++) {
        int row = m0 + rbase + i;
        if (row < N_NODES) {
            float s = norm_src[row];
            float4 v = acc[i];
            v.x *= s; v.y *= s; v.z *= s; v.w *= s;
            *reinterpret_cast<float4*>(&xw[(size_t)row * HID + cbase]) = v;
        }
    }
}

// ---------------- fused gather1 + relu + layer2 GEMV ----------------
// one block (128 threads) per node; thread j owns feature j
__global__ __launch_bounds__(128) void gather1_fused_kernel(
        const int* __restrict__ bucket, const int* __restrict__ indeg,
        const float* __restrict__ xw, const float* __restrict__ norm_dst,
        const float* __restrict__ norm_src, const float* __restrict__ b1,
        const float* __restrict__ W2,
        const int* __restrict__ ovf_cnt, const int* __restrict__ ovf_src,
        const int* __restrict__ ovf_dst,
        float* __restrict__ hw2) {
    const int n = blockIdx.x;
    const int j = threadIdx.x;
    const int deg_raw = indeg[n];
    const int deg = deg_raw < CAP ? deg_raw : CAP;

    const int* bk = bucket + (size_t)n * CAP;
    float acc = 0.f;
    int k = 0;
    for (; k + 4 <= deg; k += 4) {
        int4 s4 = *reinterpret_cast<const int4*>(&bk[k]);
        acc += xw[(size_t)s4.x * HID + j];
        acc += xw[(size_t)s4.y * HID + j];
        acc += xw[(size_t)s4.z * HID + j];
        acc += xw[(size_t)s4.w * HID + j];
    }
    for (; k < deg; k++)
        acc += xw[(size_t)bk[k] * HID + j];

    if (deg_raw > CAP) {  // effectively never; deterministic correctness fallback
        int cnt = *ovf_cnt; if (cnt > MAXOVF) cnt = MAXOVF;
        for (int q = 0; q < cnt; q++)
            if (ovf_dst[q] == n) acc += xw[(size_t)ovf_src[q] * HID + j];
    }

    float h = fmaxf(acc * norm_dst[n] + b1[j], 0.f);
    float p0 = h * W2[j * 2 + 0];
    float p1 = h * W2[j * 2 + 1];

#pragma unroll
    for (int off = 32; off > 0; off >>= 1) {
        p0 += __shfl_down(p0, off);
        p1 += __shfl_down(p1, off);
    }
    __shared__ float red[4];
    int w = j >> 6;
    if ((j & 63) == 0) { red[w * 2] = p0; red[w * 2 + 1] = p1; }
    __syncthreads();
    if (j == 0) {
        float ns = norm_src[n];
        hw2[(size_t)n * 2 + 0] = (red[0] + red[2]) * ns;
        hw2[(size_t)n * 2 + 1] = (red[1] + red[3]) * ns;
    }
}

// ---------------- fused gather2 + softmax: one wave per node ----------------
__global__ void gather2_softmax_kernel(
        const int* __restrict__ bucket, const int* __restrict__ indeg,
        const float* __restrict__ hw2, const float* __restrict__ norm_dst,
        const float* __restrict__ b2,
        const int* __restrict__ ovf_cnt, const int* __restrict__ ovf_src,
        const int* __restrict__ ovf_dst,
        float* __restrict__ out) {
    int n = (blockIdx.x * blockDim.x + threadIdx.x) >> 6;
    int lane = threadIdx.x & 63;
    if (n >= N_NODES) return;
    int deg_raw = indeg[n];
    int deg = deg_raw < CAP ? deg_raw : CAP;

    float a0 = 0.f, a1 = 0.f;
    if (lane < deg) {
        int s = bucket[(size_t)n * CAP + lane];
        float2 v = *reinterpret_cast<const float2*>(&hw2[(size_t)s * 2]);
        a0 = v.x; a1 = v.y;
    }
#pragma unroll
    for (int off = 32; off > 0; off >>= 1) {
        a0 += __shfl_down(a0, off);
        a1 += __shfl_down(a1, off);
    }
    if (lane == 0) {
        if (deg_raw > CAP) {  // effectively never
            int cnt = *ovf_cnt; if (cnt > MAXOVF) cnt = MAXOVF;
            for (int q = 0; q < cnt; q++)
                if (ovf_dst[q] == n) {
                    float2 v = *reinterpret_cast<const float2*>(&hw2[(size_t)ovf_src[q] * 2]);
                    a0 += v.x; a1 += v.y;
                }
        }
        float nd = norm_dst[n];
        float z0 = a0 * nd + b2[0];
        float z1 = a1 * nd + b2[1];
        float m = fmaxf(z0, z1);
        float e0 = expf(z0 - m), e1 = expf(z1 - m);
        float inv = 1.f / (e0 + e1);
        reinterpret_cast<float2*>(out)[n] = make_float2(e0 * inv, e1 * inv);
    }
}

extern "C" void kernel_launch(void* const* d_in, const int* in_sizes, int n_in,
                              void* d_out, int out_size, void* d_ws, size_t ws_size,
                              hipStream_t stream) {
    const float* X   = (const float*)d_in[0];
    const float* W1  = (const float*)d_in[1];
    const float* b1  = (const float*)d_in[2];
    const float* W2  = (const float*)d_in[3];
    const float* b2  = (const float*)d_in[4];
    const int*   src = (const int*)d_in[5];
    const int*   dst = (const int*)d_in[6];
    float* out = (float*)d_out;

    const size_t N = N_NODES;
    char* ws = (char*)d_ws;
    // zeroed region first: outdeg, cursor(indeg), ovf_cnt
    int*   outdeg   = (int*)ws;                       ws += N * 4;
    int*   cursor   = (int*)ws;                       ws += N * 4;   // becomes in-degree
    int*   ovf_cnt  = (int*)ws;                       ws += 16;
    size_t zero_bytes = (char*)ws - (char*)d_ws;
    float* norm_src = (float*)ws;                     ws += N * 4;
    float* norm_dst = (float*)ws;                     ws += N * 4;
    float* hw2      = (float*)ws;                     ws += N * 2 * 4;
    float* xw       = (float*)ws;                     ws += N * (size_t)HID * 4;   // 51.2 MB
    int*   bucket   = (int*)ws;                       ws += N * (size_t)CAP * 4;   // 25.6 MB
    int*   ovf_src  = (int*)ws;                       ws += (size_t)MAXOVF * 4;
    int*   ovf_dst  = (int*)ws;                       ws += (size_t)MAXOVF * 4;

    hipMemsetAsync(d_ws, 0, zero_bytes, stream);

    build_kernel<<<(N_EDGES + 255) / 256, 256, 0, stream>>>(
        src, dst, outdeg, cursor, bucket, ovf_cnt, ovf_src, ovf_dst);
    norm_kernel<<<(N_NODES + 255) / 256, 256, 0, stream>>>(outdeg, cursor, norm_src, norm_dst);
    gemm1_kernel<<<(N_NODES + 63) / 64, 256, 0, stream>>>(X, W1, norm_src, xw);
    gather1_fused_kernel<<<N_NODES, 128, 0, stream>>>(
        bucket, cursor, xw, norm_dst, norm_src, b1, W2, ovf_cnt, ovf_src, ovf_dst, hw2);
    gather2_softmax_kernel<<<(N_NODES * 64 + 255) / 256, 256, 0, stream>>>(
        bucket, cursor, hw2, norm_dst, b2, ovf_cnt, ovf_src, ovf_dst, out);
}

// Round 3
// 650.337 us; speedup vs baseline: 5.2936x; 1.1111x over previous
//
#include <hip/hip_runtime.h>
#include <math.h>

#define N_NODES 100000
#define N_EDGES 1600000
#define IN_F    512
#define HID     128
#define CAP     64          // bucket capacity per destination node
#define MAXOVF  (1 << 20)   // overflow edge list capacity (never used in practice)

typedef __attribute__((ext_vector_type(8))) _Float16 half8;
typedef __attribute__((ext_vector_type(4))) float float4v;

// ---------------- build: out-degree histogram + per-dst source buckets ----------------
__global__ void build_kernel(const int* __restrict__ src, const int* __restrict__ dst,
                             int* __restrict__ outdeg, int* __restrict__ cursor,
                             int* __restrict__ bucket, int* __restrict__ ovf_cnt,
                             int* __restrict__ ovf_src, int* __restrict__ ovf_dst) {
    int e = blockIdx.x * blockDim.x + threadIdx.x;
    if (e < N_EDGES) {
        int s = src[e], d = dst[e];
        atomicAdd(&outdeg[s], 1);
        int slot = atomicAdd(&cursor[d], 1);
        if (slot < CAP) {
            bucket[(size_t)d * CAP + slot] = s;
        } else {
            int k = atomicAdd(ovf_cnt, 1);
            if (k < MAXOVF) { ovf_src[k] = s; ovf_dst[k] = d; }
        }
    }
}

// ---------------- norms from integer degrees ----------------
__global__ void norm_kernel(const int* __restrict__ outdeg, const int* __restrict__ indeg,
                            float* __restrict__ norm_src, float* __restrict__ norm_dst) {
    int n = blockIdx.x * blockDim.x + threadIdx.x;
    if (n < N_NODES) {
        norm_src[n] = rsqrtf(fmaxf((float)outdeg[n], 1.0f));
        norm_dst[n] = rsqrtf(fmaxf((float)indeg[n], 1.0f));
    }
}

// ---------------- W1 -> f16, transposed to [col][k] ----------------
__global__ void cvtW1_kernel(const float* __restrict__ W1, _Float16* __restrict__ W1T) {
    int i = blockIdx.x * blockDim.x + threadIdx.x;   // over 512*128
    if (i < IN_F * HID) {
        int k = i >> 7, c = i & 127;
        W1T[(size_t)c * IN_F + k] = (_Float16)W1[i];
    }
}

// ---------------- GEMM1 via MFMA f16: xw[n][j] = norm_src[n] * sum_k X[n][k]*W1[k][j] ----
// BM=128, BN=128, BK=32; 256 threads = 4 waves; wave w: rows [w*32, w*32+32), all 128 cols.
// mfma_f32_16x16x32_f16: A[m=lane&15][k=(lane>>4)*8+j], B[k=(lane>>4)*8+j][n=lane&15],
//                        D col=lane&15, row=(lane>>4)*4+reg.
#define APAD 40   // 32 + 8 f16 pad -> row stride 80 B spreads banks
__global__ __launch_bounds__(256) void gemm1_mfma_kernel(const float* __restrict__ X,
                                                         const _Float16* __restrict__ W1T,
                                                         const float* __restrict__ norm_src,
                                                         float* __restrict__ xw) {
    __shared__ _Float16 As[128 * APAD];

    const int t    = threadIdx.x;
    const int wave = t >> 6;
    const int lane = t & 63;
    const int m0   = blockIdx.x * 128;
    const int quad = lane >> 4;      // 0..3
    const int l16  = lane & 15;

    float4v acc[2][8];
#pragma unroll
    for (int r = 0; r < 2; r++)
#pragma unroll
        for (int c = 0; c < 8; c++) acc[r][c] = (float4v)0.f;

    const int srow = t >> 1;            // 0..127 staging row
    const int sc16 = (t & 1) * 16;      // 0 or 16
    const int sgrow = m0 + srow;
    const bool svalid = sgrow < N_NODES;
    const float* xbase = X + (size_t)sgrow * IN_F + sc16;

    for (int kt = 0; kt < IN_F; kt += 32) {
        __syncthreads();   // protect As from previous iteration's readers
        // stage A: 128x32 fp32 -> f16 LDS; each thread handles 16 elems
        float4 v0 = make_float4(0.f, 0.f, 0.f, 0.f), v1 = v0, v2 = v0, v3 = v0;
        if (svalid) {
            const float4* xp = reinterpret_cast<const float4*>(xbase + kt);
            v0 = xp[0]; v1 = xp[1]; v2 = xp[2]; v3 = xp[3];
        }
        half8 h0, h1;
        h0[0] = (_Float16)v0.x; h0[1] = (_Float16)v0.y; h0[2] = (_Float16)v0.z; h0[3] = (_Float16)v0.w;
        h0[4] = (_Float16)v1.x; h0[5] = (_Float16)v1.y; h0[6] = (_Float16)v1.z; h0[7] = (_Float16)v1.w;
        h1[0] = (_Float16)v2.x; h1[1] = (_Float16)v2.y; h1[2] = (_Float16)v2.z; h1[3] = (_Float16)v2.w;
        h1[4] = (_Float16)v3.x; h1[5] = (_Float16)v3.y; h1[6] = (_Float16)v3.z; h1[7] = (_Float16)v3.w;
        *reinterpret_cast<half8*>(&As[srow * APAD + sc16 + 0]) = h0;
        *reinterpret_cast<half8*>(&As[srow * APAD + sc16 + 8]) = h1;
        __syncthreads();

        // B fragments straight from L2-resident W1T (no LDS)
        half8 bfrag[8];
#pragma unroll
        for (int ct = 0; ct < 8; ct++) {
            int col = ct * 16 + l16;
            bfrag[ct] = *reinterpret_cast<const half8*>(&W1T[(size_t)col * IN_F + kt + quad * 8]);
        }
        // A fragments from LDS
        half8 afrag[2];
#pragma unroll
        for (int r = 0; r < 2; r++) {
            int row_local = wave * 32 + r * 16 + l16;
            afrag[r] = *reinterpret_cast<const half8*>(&As[row_local * APAD + quad * 8]);
        }
#pragma unroll
        for (int r = 0; r < 2; r++)
#pragma unroll
            for (int ct = 0; ct < 8; ct++)
                acc[r][ct] = __builtin_amdgcn_mfma_f32_16x16x32_f16(afrag[r], bfrag[ct], acc[r][ct], 0, 0, 0);
    }

    // epilogue: scale by norm_src, store
#pragma unroll
    for (int r = 0; r < 2; r++) {
#pragma unroll
        for (int i = 0; i < 4; i++) {
            int grow = m0 + wave * 32 + r * 16 + quad * 4 + i;
            if (grow < N_NODES) {
                float s = norm_src[grow];
                float* orow = &xw[(size_t)grow * HID];
#pragma unroll
                for (int ct = 0; ct < 8; ct++)
                    orow[ct * 16 + l16] = acc[r][ct][i] * s;
            }
        }
    }
}

// ---------------- fused gather1 + relu + layer2 GEMV ----------------
// one block (128 threads) per node; thread j owns feature j
__global__ __launch_bounds__(128) void gather1_fused_kernel(
        const int* __restrict__ bucket, const int* __restrict__ indeg,
        const float* __restrict__ xw, const float* __restrict__ norm_dst,
        const float* __restrict__ norm_src, const float* __restrict__ b1,
        const float* __restrict__ W2,
        const int* __restrict__ ovf_cnt, const int* __restrict__ ovf_src,
        const int* __restrict__ ovf_dst,
        float* __restrict__ hw2) {
    const int n = blockIdx.x;
    const int j = threadIdx.x;
    const int deg_raw = indeg[n];
    const int deg = deg_raw < CAP ? deg_raw : CAP;

    const int* bk = bucket + (size_t)n * CAP;
    float acc = 0.f;
    int k = 0;
    for (; k + 4 <= deg; k += 4) {
        int4 s4 = *reinterpret_cast<const int4*>(&bk[k]);
        acc += xw[(size_t)s4.x * HID + j];
        acc += xw[(size_t)s4.y * HID + j];
        acc += xw[(size_t)s4.z * HID + j];
        acc += xw[(size_t)s4.w * HID + j];
    }
    for (; k < deg; k++)
        acc += xw[(size_t)bk[k] * HID + j];

    if (deg_raw > CAP) {  // effectively never; deterministic correctness fallback
        int cnt = *ovf_cnt; if (cnt > MAXOVF) cnt = MAXOVF;
        for (int q = 0; q < cnt; q++)
            if (ovf_dst[q] == n) acc += xw[(size_t)ovf_src[q] * HID + j];
    }

    float h = fmaxf(acc * norm_dst[n] + b1[j], 0.f);
    float p0 = h * W2[j * 2 + 0];
    float p1 = h * W2[j * 2 + 1];

#pragma unroll
    for (int off = 32; off > 0; off >>= 1) {
        p0 += __shfl_down(p0, off);
        p1 += __shfl_down(p1, off);
    }
    __shared__ float red[4];
    int w = j >> 6;
    if ((j & 63) == 0) { red[w * 2] = p0; red[w * 2 + 1] = p1; }
    __syncthreads();
    if (j == 0) {
        float ns = norm_src[n];
        hw2[(size_t)n * 2 + 0] = (red[0] + red[2]) * ns;
        hw2[(size_t)n * 2 + 1] = (red[1] + red[3]) * ns;
    }
}

// ---------------- fused gather2 + softmax: one wave per node ----------------
__global__ void gather2_softmax_kernel(
        const int* __restrict__ bucket, const int* __restrict__ indeg,
        const float* __restrict__ hw2, const float* __restrict__ norm_dst,
        const float* __restrict__ b2,
        const int* __restrict__ ovf_cnt, const int* __restrict__ ovf_src,
        const int* __restrict__ ovf_dst,
        float* __restrict__ out) {
    int n = (blockIdx.x * blockDim.x + threadIdx.x) >> 6;
    int lane = threadIdx.x & 63;
    if (n >= N_NODES) return;
    int deg_raw = indeg[n];
    int deg = deg_raw < CAP ? deg_raw : CAP;

    float a0 = 0.f, a1 = 0.f;
    if (lane < deg) {
        int s = bucket[(size_t)n * CAP + lane];
        float2 v = *reinterpret_cast<const float2*>(&hw2[(size_t)s * 2]);
        a0 = v.x; a1 = v.y;
    }
#pragma unroll
    for (int off = 32; off > 0; off >>= 1) {
        a0 += __shfl_down(a0, off);
        a1 += __shfl_down(a1, off);
    }
    if (lane == 0) {
        if (deg_raw > CAP) {  // effectively never
            int cnt = *ovf_cnt; if (cnt > MAXOVF) cnt = MAXOVF;
            for (int q = 0; q < cnt; q++)
                if (ovf_dst[q] == n) {
                    float2 v = *reinterpret_cast<const float2*>(&hw2[(size_t)ovf_src[q] * 2]);
                    a0 += v.x; a1 += v.y;
                }
        }
        float nd = norm_dst[n];
        float z0 = a0 * nd + b2[0];
        float z1 = a1 * nd + b2[1];
        float m = fmaxf(z0, z1);
        float e0 = expf(z0 - m), e1 = expf(z1 - m);
        float inv = 1.f / (e0 + e1);
        reinterpret_cast<float2*>(out)[n] = make_float2(e0 * inv, e1 * inv);
    }
}

extern "C" void kernel_launch(void* const* d_in, const int* in_sizes, int n_in,
                              void* d_out, int out_size, void* d_ws, size_t ws_size,
                              hipStream_t stream) {
    const float* X   = (const float*)d_in[0];
    const float* W1  = (const float*)d_in[1];
    const float* b1  = (const float*)d_in[2];
    const float* W2  = (const float*)d_in[3];
    const float* b2  = (const float*)d_in[4];
    const int*   src = (const int*)d_in[5];
    const int*   dst = (const int*)d_in[6];
    float* out = (float*)d_out;

    const size_t N = N_NODES;
    char* ws = (char*)d_ws;
    // zeroed region first: outdeg, cursor(indeg), ovf_cnt
    int*   outdeg   = (int*)ws;                       ws += N * 4;
    int*   cursor   = (int*)ws;                       ws += N * 4;   // becomes in-degree
    int*   ovf_cnt  = (int*)ws;                       ws += 16;
    size_t zero_bytes = (char*)ws - (char*)d_ws;
    float* norm_src = (float*)ws;                     ws += N * 4;
    float* norm_dst = (float*)ws;                     ws += N * 4;
    float* hw2      = (float*)ws;                     ws += N * 2 * 4;
    _Float16* W1T   = (_Float16*)ws;                  ws += (size_t)IN_F * HID * 2; // 128 KB
    float* xw       = (float*)ws;                     ws += N * (size_t)HID * 4;   // 51.2 MB
    int*   bucket   = (int*)ws;                       ws += N * (size_t)CAP * 4;   // 25.6 MB
    int*   ovf_src  = (int*)ws;                       ws += (size_t)MAXOVF * 4;
    int*   ovf_dst  = (int*)ws;                       ws += (size_t)MAXOVF * 4;

    hipMemsetAsync(d_ws, 0, zero_bytes, stream);

    build_kernel<<<(N_EDGES + 255) / 256, 256, 0, stream>>>(
        src, dst, outdeg, cursor, bucket, ovf_cnt, ovf_src, ovf_dst);
    norm_kernel<<<(N_NODES + 255) / 256, 256, 0, stream>>>(outdeg, cursor, norm_src, norm_dst);
    cvtW1_kernel<<<(IN_F * HID + 255) / 256, 256, 0, stream>>>(W1, W1T);
    gemm1_mfma_kernel<<<(N_NODES + 127) / 128, 256, 0, stream>>>(X, W1T, norm_src, xw);
    gather1_fused_kernel<<<N_NODES, 128, 0, stream>>>(
        bucket, cursor, xw, norm_dst, norm_src, b1, W2, ovf_cnt, ovf_src, ovf_dst, hw2);
    gather2_softmax_kernel<<<(N_NODES * 64 + 255) / 256, 256, 0, stream>>>(
        bucket, cursor, hw2, norm_dst, b2, ovf_cnt, ovf_src, ovf_dst, out);
}

// Round 4
// 606.185 us; speedup vs baseline: 5.6792x; 1.0728x over previous
//
#include <hip/hip_runtime.h>
#include <math.h>

#define N_NODES 100000
#define N_EDGES 1600000
#define IN_F    512
#define HID     128
#define NBLK    ((N_NODES + 255) / 256)   // 391 scan blocks

typedef __attribute__((ext_vector_type(8))) _Float16 half8;
typedef __attribute__((ext_vector_type(2))) _Float16 half2v;
typedef __attribute__((ext_vector_type(4))) float float4v;

// ---------------- pass A: degrees + per-edge rank within its dst ----------------
__global__ void rank_kernel(const int* __restrict__ src, const int* __restrict__ dst,
                            int* __restrict__ outdeg, int* __restrict__ indeg,
                            int* __restrict__ rank) {
    int e = blockIdx.x * blockDim.x + threadIdx.x;
    if (e < N_EDGES) {
        atomicAdd(&outdeg[src[e]], 1);
        rank[e] = atomicAdd(&indeg[dst[e]], 1);
    }
}

// ---------------- norms ----------------
__global__ void norm_kernel(const int* __restrict__ outdeg, const int* __restrict__ indeg,
                            float* __restrict__ norm_src, float* __restrict__ norm_dst) {
    int n = blockIdx.x * blockDim.x + threadIdx.x;
    if (n < N_NODES) {
        norm_src[n] = rsqrtf(fmaxf((float)outdeg[n], 1.0f));
        norm_dst[n] = rsqrtf(fmaxf((float)indeg[n], 1.0f));
    }
}

// ---------------- 3-kernel coalesced prefix scan of indeg -> offs[N+1] ----------------
__global__ void scanA_kernel(const int* __restrict__ indeg, int* __restrict__ bsum) {
    __shared__ int sh[256];
    int t = threadIdx.x, idx = blockIdx.x * 256 + t;
    sh[t] = (idx < N_NODES) ? indeg[idx] : 0;
    __syncthreads();
#pragma unroll
    for (int d = 128; d > 0; d >>= 1) {
        if (t < d) sh[t] += sh[t + d];
        __syncthreads();
    }
    if (t == 0) bsum[blockIdx.x] = sh[0];
}

__global__ __launch_bounds__(512) void scanB_kernel(const int* __restrict__ bsum,
                                                    int* __restrict__ bbase) {
    __shared__ int sh[512];
    int t = threadIdx.x;
    sh[t] = (t < NBLK) ? bsum[t] : 0;
    __syncthreads();
#pragma unroll
    for (int d = 1; d < 512; d <<= 1) {
        int v = (t >= d) ? sh[t - d] : 0;
        __syncthreads();
        sh[t] += v;
        __syncthreads();
    }
    if (t < NBLK) bbase[t] = (t == 0) ? 0 : sh[t - 1];
}

__global__ void scanC_kernel(const int* __restrict__ indeg, const int* __restrict__ bbase,
                             int* __restrict__ offs) {
    __shared__ int sh[256];
    int t = threadIdx.x, idx = blockIdx.x * 256 + t;
    int v = (idx < N_NODES) ? indeg[idx] : 0;
    sh[t] = v;
    __syncthreads();
#pragma unroll
    for (int d = 1; d < 256; d <<= 1) {
        int u = (t >= d) ? sh[t - d] : 0;
        __syncthreads();
        sh[t] += u;
        __syncthreads();
    }
    int incl = sh[t];
    if (idx < N_NODES) {
        int base = bbase[blockIdx.x];
        offs[idx] = base + incl - v;
        if (idx == N_NODES - 1) offs[N_NODES] = base + incl;
    }
}

// ---------------- pass B: scatter src into CSR ----------------
__global__ void scatter_csr_kernel(const int* __restrict__ src, const int* __restrict__ dst,
                                   const int* __restrict__ rank, const int* __restrict__ offs,
                                   int* __restrict__ csr) {
    int e = blockIdx.x * blockDim.x + threadIdx.x;
    if (e < N_EDGES)
        csr[offs[dst[e]] + rank[e]] = src[e];
}

// ---------------- W1 -> f16, transposed to [col][k] ----------------
__global__ void cvtW1_kernel(const float* __restrict__ W1, _Float16* __restrict__ W1T) {
    int i = blockIdx.x * blockDim.x + threadIdx.x;
    if (i < IN_F * HID) {
        int k = i >> 7, c = i & 127;
        W1T[(size_t)c * IN_F + k] = (_Float16)W1[i];
    }
}

// ---------------- GEMM1 via MFMA f16, double-buffered, f16 output ----------------
// BM=128, BN=128, BK=32; 256 threads = 4 waves; wave w owns rows [w*32, w*32+32).
#define APAD 40
__global__ __launch_bounds__(256) void gemm1_mfma_kernel(const float* __restrict__ X,
                                                         const _Float16* __restrict__ W1T,
                                                         const float* __restrict__ norm_src,
                                                         _Float16* __restrict__ xwh) {
    __shared__ _Float16 As[2][128 * APAD];

    const int t    = threadIdx.x;
    const int wave = t >> 6;
    const int lane = t & 63;
    const int m0   = blockIdx.x * 128;
    const int quad = lane >> 4;
    const int l16  = lane & 15;

    float4v acc[2][8];
#pragma unroll
    for (int r = 0; r < 2; r++)
#pragma unroll
        for (int c = 0; c < 8; c++) acc[r][c] = (float4v)0.f;

    const int srow = t >> 1;
    const int sc16 = (t & 1) * 16;
    const int sgrow = m0 + srow;
    const bool svalid = sgrow < N_NODES;
    const float* xbase = X + (size_t)sgrow * IN_F + sc16;

    // preload tile 0 (X regs + B frags)
    float4 va[4];
#pragma unroll
    for (int i = 0; i < 4; i++) va[i] = make_float4(0.f, 0.f, 0.f, 0.f);
    if (svalid) {
        const float4* xp = reinterpret_cast<const float4*>(xbase);
        va[0] = xp[0]; va[1] = xp[1]; va[2] = xp[2]; va[3] = xp[3];
    }
    half8 bfrag[8];
#pragma unroll
    for (int ct = 0; ct < 8; ct++)
        bfrag[ct] = *reinterpret_cast<const half8*>(&W1T[(size_t)(ct * 16 + l16) * IN_F + quad * 8]);

    // store tile 0 into As[0]
    {
        half8 h0, h1;
        h0[0]=(_Float16)va[0].x; h0[1]=(_Float16)va[0].y; h0[2]=(_Float16)va[0].z; h0[3]=(_Float16)va[0].w;
        h0[4]=(_Float16)va[1].x; h0[5]=(_Float16)va[1].y; h0[6]=(_Float16)va[1].z; h0[7]=(_Float16)va[1].w;
        h1[0]=(_Float16)va[2].x; h1[1]=(_Float16)va[2].y; h1[2]=(_Float16)va[2].z; h1[3]=(_Float16)va[2].w;
        h1[4]=(_Float16)va[3].x; h1[5]=(_Float16)va[3].y; h1[6]=(_Float16)va[3].z; h1[7]=(_Float16)va[3].w;
        *reinterpret_cast<half8*>(&As[0][srow * APAD + sc16 + 0]) = h0;
        *reinterpret_cast<half8*>(&As[0][srow * APAD + sc16 + 8]) = h1;
    }

    int cur = 0;
    for (int it = 0; it < IN_F / 32; it++) {
        const int ktn = (it + 1) * 32;
        const bool more = ktn < IN_F;
        __syncthreads();   // As[cur] visible; As[cur^1] readers (it-1) done

        // issue next tile's global loads early (overlap with MFMA below)
        float4 vb[4];
        half8 bnext[8];
        if (more) {
            if (svalid) {
                const float4* xp = reinterpret_cast<const float4*>(xbase + ktn);
                vb[0] = xp[0]; vb[1] = xp[1]; vb[2] = xp[2]; vb[3] = xp[3];
            } else {
                vb[0] = vb[1] = vb[2] = vb[3] = make_float4(0.f, 0.f, 0.f, 0.f);
            }
#pragma unroll
            for (int ct = 0; ct < 8; ct++)
                bnext[ct] = *reinterpret_cast<const half8*>(
                    &W1T[(size_t)(ct * 16 + l16) * IN_F + ktn + quad * 8]);
        }

        // compute on As[cur] with bfrag
        half8 afrag[2];
#pragma unroll
        for (int r = 0; r < 2; r++)
            afrag[r] = *reinterpret_cast<const half8*>(
                &As[cur][(wave * 32 + r * 16 + l16) * APAD + quad * 8]);
#pragma unroll
        for (int r = 0; r < 2; r++)
#pragma unroll
            for (int ct = 0; ct < 8; ct++)
                acc[r][ct] = __builtin_amdgcn_mfma_f32_16x16x32_f16(afrag[r], bfrag[ct], acc[r][ct], 0, 0, 0);

        if (more) {
            half8 h0, h1;
            h0[0]=(_Float16)vb[0].x; h0[1]=(_Float16)vb[0].y; h0[2]=(_Float16)vb[0].z; h0[3]=(_Float16)vb[0].w;
            h0[4]=(_Float16)vb[1].x; h0[5]=(_Float16)vb[1].y; h0[6]=(_Float16)vb[1].z; h0[7]=(_Float16)vb[1].w;
            h1[0]=(_Float16)vb[2].x; h1[1]=(_Float16)vb[2].y; h1[2]=(_Float16)vb[2].z; h1[3]=(_Float16)vb[2].w;
            h1[4]=(_Float16)vb[3].x; h1[5]=(_Float16)vb[3].y; h1[6]=(_Float16)vb[3].z; h1[7]=(_Float16)vb[3].w;
            *reinterpret_cast<half8*>(&As[cur ^ 1][srow * APAD + sc16 + 0]) = h0;
            *reinterpret_cast<half8*>(&As[cur ^ 1][srow * APAD + sc16 + 8]) = h1;
#pragma unroll
            for (int ct = 0; ct < 8; ct++) bfrag[ct] = bnext[ct];
        }
        cur ^= 1;
    }

    // epilogue: scale by norm_src, store f16
#pragma unroll
    for (int r = 0; r < 2; r++) {
#pragma unroll
        for (int i = 0; i < 4; i++) {
            int grow = m0 + wave * 32 + r * 16 + quad * 4 + i;
            if (grow < N_NODES) {
                float s = norm_src[grow];
                _Float16* orow = &xwh[(size_t)grow * HID];
#pragma unroll
                for (int ct = 0; ct < 8; ct++)
                    orow[ct * 16 + l16] = (_Float16)(acc[r][ct][i] * s);
            }
        }
    }
}

// ---------------- fused gather1 + relu + layer2 GEMV: one wave per node ----------------
// lane j owns features 2j, 2j+1 (f16x2 loads)
__global__ __launch_bounds__(256) void gather1_kernel(
        const int* __restrict__ csr, const int* __restrict__ offs,
        const _Float16* __restrict__ xwh, const float* __restrict__ norm_dst,
        const float* __restrict__ norm_src, const float* __restrict__ b1,
        const float* __restrict__ W2, float* __restrict__ hw2) {
    const int w    = (blockIdx.x * blockDim.x + threadIdx.x) >> 6;   // node
    const int lane = threadIdx.x & 63;
    if (w >= N_NODES) return;
    const int off = offs[w], end = offs[w + 1];
    const int j2 = lane * 2;

    float a0 = 0.f, a1 = 0.f;
    int k = off;
    for (; k + 4 <= end; k += 4) {
        int s0 = csr[k], s1 = csr[k + 1], s2 = csr[k + 2], s3 = csr[k + 3];
        half2v v0 = *reinterpret_cast<const half2v*>(&xwh[(size_t)s0 * HID + j2]);
        half2v v1 = *reinterpret_cast<const half2v*>(&xwh[(size_t)s1 * HID + j2]);
        half2v v2 = *reinterpret_cast<const half2v*>(&xwh[(size_t)s2 * HID + j2]);
        half2v v3 = *reinterpret_cast<const half2v*>(&xwh[(size_t)s3 * HID + j2]);
        a0 += (float)v0[0] + (float)v1[0] + (float)v2[0] + (float)v3[0];
        a1 += (float)v0[1] + (float)v1[1] + (float)v2[1] + (float)v3[1];
    }
    for (; k < end; k++) {
        half2v v = *reinterpret_cast<const half2v*>(&xwh[(size_t)csr[k] * HID + j2]);
        a0 += (float)v[0]; a1 += (float)v[1];
    }

    const float nd = norm_dst[w];
    float2 b = *reinterpret_cast<const float2*>(&b1[j2]);
    float h0 = fmaxf(a0 * nd + b.x, 0.f);
    float h1 = fmaxf(a1 * nd + b.y, 0.f);
    float2 w2a = reinterpret_cast<const float2*>(W2)[j2];
    float2 w2b = reinterpret_cast<const float2*>(W2)[j2 + 1];
    float p0 = h0 * w2a.x + h1 * w2b.x;
    float p1 = h0 * w2a.y + h1 * w2b.y;
#pragma unroll
    for (int offd = 32; offd > 0; offd >>= 1) {
        p0 += __shfl_down(p0, offd);
        p1 += __shfl_down(p1, offd);
    }
    if (lane == 0) {
        float ns = norm_src[w];
        reinterpret_cast<float2*>(hw2)[w] = make_float2(p0 * ns, p1 * ns);
    }
}

// ---------------- fused gather2 + softmax: 4 nodes per wave (16 lanes each) ----------------
__global__ void gather2_softmax_kernel(
        const int* __restrict__ csr, const int* __restrict__ offs,
        const float* __restrict__ hw2, const float* __restrict__ norm_dst,
        const float* __restrict__ b2, float* __restrict__ out) {
    const int w    = (blockIdx.x * blockDim.x + threadIdx.x) >> 6;
    const int lane = threadIdx.x & 63;
    const int sub  = lane >> 4, k0 = lane & 15;
    const int n = w * 4 + sub;
    if (n >= N_NODES) return;
    const int off = offs[n], end = offs[n + 1];

    float a0 = 0.f, a1 = 0.f;
    for (int k = off + k0; k < end; k += 16) {
        int s = csr[k];
        float2 v = reinterpret_cast<const float2*>(hw2)[s];
        a0 += v.x; a1 += v.y;
    }
#pragma unroll
    for (int d = 1; d < 16; d <<= 1) {
        a0 += __shfl_xor(a0, d);
        a1 += __shfl_xor(a1, d);
    }
    if (k0 == 0) {
        float nd = norm_dst[n];
        float z0 = a0 * nd + b2[0];
        float z1 = a1 * nd + b2[1];
        float m = fmaxf(z0, z1);
        float e0 = expf(z0 - m), e1 = expf(z1 - m);
        float inv = 1.f / (e0 + e1);
        reinterpret_cast<float2*>(out)[n] = make_float2(e0 * inv, e1 * inv);
    }
}

extern "C" void kernel_launch(void* const* d_in, const int* in_sizes, int n_in,
                              void* d_out, int out_size, void* d_ws, size_t ws_size,
                              hipStream_t stream) {
    const float* X   = (const float*)d_in[0];
    const float* W1  = (const float*)d_in[1];
    const float* b1  = (const float*)d_in[2];
    const float* W2  = (const float*)d_in[3];
    const float* b2  = (const float*)d_in[4];
    const int*   src = (const int*)d_in[5];
    const int*   dst = (const int*)d_in[6];
    float* out = (float*)d_out;

    const size_t N = N_NODES;
    char* ws = (char*)d_ws;
    // zeroed region first: outdeg, indeg
    int*   outdeg   = (int*)ws;                       ws += N * 4;
    int*   indeg    = (int*)ws;                       ws += N * 4;
    size_t zero_bytes = (char*)ws - (char*)d_ws;      // 800 KB
    int*   rank     = (int*)ws;                       ws += (size_t)N_EDGES * 4;   // 6.4 MB
    int*   offs     = (int*)ws;                       ws += (N + 1) * 4;
    int*   bsum     = (int*)ws;                       ws += NBLK * 4;
    int*   bbase    = (int*)ws;                       ws += NBLK * 4;
    float* norm_src = (float*)ws;                     ws += N * 4;
    float* norm_dst = (float*)ws;                     ws += N * 4;
    float* hw2      = (float*)ws;                     ws += N * 2 * 4;
    _Float16* W1T   = (_Float16*)ws;                  ws += (size_t)IN_F * HID * 2; // 128 KB
    _Float16* xwh   = (_Float16*)ws;                  ws += N * (size_t)HID * 2;    // 25.6 MB
    int*   csr      = (int*)ws;                       ws += (size_t)N_EDGES * 4;    // 6.4 MB

    hipMemsetAsync(d_ws, 0, zero_bytes, stream);

    rank_kernel<<<(N_EDGES + 255) / 256, 256, 0, stream>>>(src, dst, outdeg, indeg, rank);
    norm_kernel<<<NBLK, 256, 0, stream>>>(outdeg, indeg, norm_src, norm_dst);
    scanA_kernel<<<NBLK, 256, 0, stream>>>(indeg, bsum);
    scanB_kernel<<<1, 512, 0, stream>>>(bsum, bbase);
    scanC_kernel<<<NBLK, 256, 0, stream>>>(indeg, bbase, offs);
    scatter_csr_kernel<<<(N_EDGES + 255) / 256, 256, 0, stream>>>(src, dst, rank, offs, csr);
    cvtW1_kernel<<<(IN_F * HID + 255) / 256, 256, 0, stream>>>(W1, W1T);
    gemm1_mfma_kernel<<<(N_NODES + 127) / 128, 256, 0, stream>>>(X, W1T, norm_src, xwh);
    gather1_kernel<<<(N_NODES * 64 + 255) / 256, 256, 0, stream>>>(
        csr, offs, xwh, norm_dst, norm_src, b1, W2, hw2);
    gather2_softmax_kernel<<<((N + 3) / 4 * 64 + 255) / 256, 256, 0, stream>>>(
        csr, offs, hw2, norm_dst, b2, out);
}